// Round 2
// baseline (723.914 us; speedup 1.0000x reference)
//
#include <hip/hip_runtime.h>
#include <cstdint>
#include <cstddef>

// Problem constants
#define BB 4096
#define DD 2048
#define NHH 16
#define NTT 4
#define DKK 128

using u16 = unsigned short;
using u32 = unsigned int;

typedef __bf16 bf16x8 __attribute__((ext_vector_type(8)));
typedef float f32x4 __attribute__((ext_vector_type(4)));

__device__ __forceinline__ float b2f(u16 u) {
    union { float f; u32 i; } c; c.i = ((u32)u) << 16; return c.f;
}
__device__ __forceinline__ u16 f2b(float f) {
    union { float f; u32 i; } c; c.f = f;
    u32 x = c.i;
    u32 r = (x + 0x7fffu + ((x >> 16) & 1u)) >> 16;  // RNE
    return (u16)r;
}
// pack two f32 -> two bf16 (round-half-up via +0x8000, v_perm byte select)
__device__ __forceinline__ u32 pk(float lo, float hi) {
    u32 a = __builtin_bit_cast(u32, lo) + 0x8000u;
    u32 b = __builtin_bit_cast(u32, hi) + 0x8000u;
    return __builtin_amdgcn_perm(b, a, 0x07060302u);  // {b[31:16], a[31:16]}
}

__device__ __forceinline__ void load_lds16(const void* g, void* l) {
    __builtin_amdgcn_global_load_lds((const __attribute__((address_space(1))) void*)g,
                                     (__attribute__((address_space(3))) void*)l,
                                     16, 0, 0);
}

// ---------------------------------------------------------------------------
// cvt_all: one dispatch converts e0..e3 -> Ebf (M-interleaved rows 4b+t) and
// Wq/Wk/Wv/Wo -> W4 (4 contiguous bf16 slots).
// blocks 0..16383: evidence rows.  blocks 16384..24575: weights (2048/blk).
// ---------------------------------------------------------------------------
__global__ __launch_bounds__(256) void cvt_all(
    const float* __restrict__ e0, const float* __restrict__ e1,
    const float* __restrict__ e2, const float* __restrict__ e3,
    const float* __restrict__ Wq, const float* __restrict__ Wk,
    const float* __restrict__ Wv, const float* __restrict__ Wo,
    u16* __restrict__ Ebf, u16* __restrict__ W4)
{
    const int blk = blockIdx.x;
    const float* src;
    u16* dst;
    size_t i;
    if (blk < 16384) {
        const int t = blk & 3, b = blk >> 2;
        src = ((t == 0) ? e0 : (t == 1) ? e1 : (t == 2) ? e2 : e3) + (size_t)b * DD;
        dst = Ebf + (size_t)blk * DD;
        i = threadIdx.x * 8;
    } else {
        const int wb = blk - 16384;          // 0..8191
        const int w = wb >> 11;              // 0..3
        src = (w == 0) ? Wq : (w == 1) ? Wk : (w == 2) ? Wv : Wo;
        dst = W4 + (size_t)w * DD * DD;
        i = (size_t)(wb & 2047) * 2048 + threadIdx.x * 8;
    }
    float4 a = *(const float4*)(src + i);
    float4 c = *(const float4*)(src + i + 4);
    *(uint4*)(dst + i) = make_uint4(pk(a.x, a.y), pk(a.z, a.w),
                                    pk(c.x, c.y), pk(c.z, c.w));
}

// ---------------------------------------------------------------------------
// qkv_attn: fused Q/K/V projection + quality-gated softmax + V-combine.
// grid (16, 128): x = head h (n-tile = 128 cols = one head), y = m-tile.
// BK=64 (128B LDS rows) with XOR swizzle (slot ^= row&7), staged linearly by
// global_load_lds with a pre-swizzled per-lane source column (rule #21).
//
// Wave tiling: 2x2 waves of 64M x 64N (was 4 waves of 32M x 128N).  B-frag
// reuse rises 2->4: ds_read per kk drops 26 -> 16 (LDS pipe was co-critical
// with MFMA at ~54% each).  Accumulator budget unchanged (3*4*4 f32x4).
// Since a wave now holds only half a head's dk dims, the score dot-product
// is completed by an LDS exchange between N-partner waves (w ^ 1) in the
// one-time epilogue.
// ---------------------------------------------------------------------------
__global__ __launch_bounds__(256, 2) void qkv_attn(
    const u16* __restrict__ Ebf,
    const u16* __restrict__ Wqb, const u16* __restrict__ Wkb,
    const u16* __restrict__ Wvb,
    const float* __restrict__ bq, const float* __restrict__ bk,
    const float* __restrict__ bv, const float* __restrict__ qual,
    u16* __restrict__ ctx)
{
    __shared__ __align__(16) u16 As [128 * 64];
    __shared__ __align__(16) u16 BQs[128 * 64];
    __shared__ __align__(16) u16 BKs[128 * 64];
    __shared__ __align__(16) u16 BVs[128 * 64];
    __shared__ float exch[4][4][4][16];   // [wave][mi][quad][t*4+j]

    const int tid = threadIdx.x;
    const int h = blockIdx.x;            // head = n-tile
    const int m0 = blockIdx.y * 128;
    const int n0 = h * 128;

    const int wave = tid >> 6;
    const int lane = tid & 63;

    // staging: call i covers rows i*32..i*32+31; lane l of wave w owns
    // row i*32 + w*8 + (l>>3), LDS slot l&7.  Source chunk = (l&7)^(l>>3).
    const int srow = wave * 8 + (lane >> 3);
    const int scol = ((lane & 7) ^ (lane >> 3)) * 8;     // u16 units
    const u16* srcA = Ebf + (size_t)(m0 + srow) * DD + scol;
    const u16* srcQ = Wqb + (size_t)(n0 + srow) * DD + scol;
    const u16* srcK = Wkb + (size_t)(n0 + srow) * DD + scol;
    const u16* srcV = Wvb + (size_t)(n0 + srow) * DD + scol;

    char* ldsA = (char*)As  + wave * 1024;
    char* ldsQ = (char*)BQs + wave * 1024;
    char* ldsK = (char*)BKs + wave * 1024;
    char* ldsV = (char*)BVs + wave * 1024;

    const int lrow = lane & 15;
    const int q4 = lane >> 4;
    const int wm = (wave >> 1) * 64;     // wave's 64 M-rows
    const int wn = (wave & 1) * 64;      // wave's 64 N-cols (half head)
    // byte offset of this lane's 16B slot within a 128B row (kk=0); kk=1 is ^64
    const int soff0 = (q4 ^ (lrow & 7)) * 16;

    f32x4 aQ[4][4] = {};
    f32x4 aK[4][4] = {};
    f32x4 aV[4][4] = {};

    for (int k0 = 0; k0 < DD; k0 += 64) {
        __syncthreads();
#pragma unroll
        for (int i = 0; i < 4; ++i) {
            const size_t go = (size_t)i * 32 * DD;
            load_lds16(srcA + go, ldsA + i * 4096);
            load_lds16(srcQ + go, ldsQ + i * 4096);
            load_lds16(srcK + go, ldsK + i * 4096);
            load_lds16(srcV + go, ldsV + i * 4096);
        }
        srcA += 64; srcQ += 64; srcK += 64; srcV += 64;
        __syncthreads();

#pragma unroll
        for (int kk = 0; kk < 2; ++kk) {
            const int so = soff0 ^ (kk * 64);
            bf16x8 af[4];
#pragma unroll
            for (int mi = 0; mi < 4; ++mi)
                af[mi] = *(const bf16x8*)((const char*)As + (wm + mi * 16 + lrow) * 128 + so);
            bf16x8 bq4[4], bk4[4], bv4[4];
#pragma unroll
            for (int ni = 0; ni < 4; ++ni) {
                const int boff = (wn + ni * 16 + lrow) * 128 + so;
                bq4[ni] = *(const bf16x8*)((const char*)BQs + boff);
                bk4[ni] = *(const bf16x8*)((const char*)BKs + boff);
                bv4[ni] = *(const bf16x8*)((const char*)BVs + boff);
            }
#pragma unroll
            for (int mi = 0; mi < 4; ++mi)
#pragma unroll
                for (int ni = 0; ni < 4; ++ni) {
                    aQ[mi][ni] = __builtin_amdgcn_mfma_f32_16x16x32_bf16(af[mi], bq4[ni], aQ[mi][ni], 0, 0, 0);
                    aK[mi][ni] = __builtin_amdgcn_mfma_f32_16x16x32_bf16(af[mi], bk4[ni], aK[mi][ni], 0, 0, 0);
                    aV[mi][ni] = __builtin_amdgcn_mfma_f32_16x16x32_bf16(af[mi], bv4[ni], aV[mi][ni], 0, 0, 0);
                }
        }
    }

    // ---- epilogue: scores -> cross-wave sum -> softmax -> V combine ----
    const int quad = lane >> 4;
    const int lcol = lane & 15;

    float qb[4], kb[4], vb[4];
#pragma unroll
    for (int ni = 0; ni < 4; ++ni) {
        const int col = n0 + wn + ni * 16 + lcol;
        qb[ni] = bq[col]; kb[ni] = bk[col]; vb[ni] = bv[col];
    }

    // Phase A: per mi, partial scores over this wave's 64 cols -> exch
#pragma unroll
    for (int mi = 0; mi < 4; ++mi) {
        float ps[4][4];
#pragma unroll
        for (int t = 0; t < 4; ++t)
#pragma unroll
            for (int j = 0; j < 4; ++j) ps[t][j] = 0.f;

#pragma unroll
        for (int ni = 0; ni < 4; ++ni) {
            float qv[4], kv[4];
#pragma unroll
            for (int t = 0; t < 4; ++t) {
                qv[t] = aQ[mi][ni][t] + qb[ni];
                kv[t] = aK[mi][ni][t] + kb[ni];
            }
#pragma unroll
            for (int t = 0; t < 4; ++t)
#pragma unroll
                for (int j = 0; j < 4; ++j) ps[t][j] += qv[t] * kv[j];
        }
        // butterfly over the 16 col-lanes (bits 0..3 of lane)
#pragma unroll
        for (int t = 0; t < 4; ++t)
#pragma unroll
            for (int j = 0; j < 4; ++j) {
                ps[t][j] += __shfl_xor(ps[t][j], 1);
                ps[t][j] += __shfl_xor(ps[t][j], 2);
                ps[t][j] += __shfl_xor(ps[t][j], 4);
                ps[t][j] += __shfl_xor(ps[t][j], 8);
            }
        // one lane per quad writes the 16 values with STATIC indices
        if (lcol == 0) {
#pragma unroll
            for (int t = 0; t < 4; ++t)
#pragma unroll
                for (int j = 0; j < 4; ++j)
                    exch[wave][mi][quad][t * 4 + j] = ps[t][j];
        }
    }
    __syncthreads();

    // Phase B: full scores (own + N-partner) -> softmax -> V combine
    const float scale = 0.08838834764831845f;   // 1/sqrt(128)
#pragma unroll
    for (int mi = 0; mi < 4; ++mi) {
        const int bbat = (m0 >> 2) + (wave >> 1) * 16 + mi * 4 + quad;

        float s16[16];
#pragma unroll
        for (int v = 0; v < 16; ++v)
            s16[v] = exch[wave][mi][quad][v] + exch[wave ^ 1][mi][quad][v];

        float qj[4];
#pragma unroll
        for (int j = 0; j < 4; ++j) qj[j] = qual[bbat * 4 + j] * scale;

        float wsum[4] = {0.f, 0.f, 0.f, 0.f};
#pragma unroll
        for (int t = 0; t < 4; ++t) {
            float sm[4]; float mx = -1e30f;
#pragma unroll
            for (int j = 0; j < 4; ++j) { sm[j] = s16[t * 4 + j] * qj[j]; mx = fmaxf(mx, sm[j]); }
            float ex[4]; float se = 0.f;
#pragma unroll
            for (int j = 0; j < 4; ++j) { ex[j] = __expf(sm[j] - mx); se += ex[j]; }
            const float inv = 0.25f / se;
#pragma unroll
            for (int j = 0; j < 4; ++j) wsum[j] += ex[j] * inv;
        }

        // ctx[bbat][col] = sum_j wsum[j] * Vproj[4b+j][col] + bv[col]
        // (sum_j wsum[j] == 1, so bias coefficient is exactly 1)
#pragma unroll
        for (int ni = 0; ni < 4; ++ni) {
            const int col = n0 + wn + ni * 16 + lcol;
            float r = wsum[0] * aV[mi][ni][0] + wsum[1] * aV[mi][ni][1]
                    + wsum[2] * aV[mi][ni][2] + wsum[3] * aV[mi][ni][3] + vb[ni];
            ctx[(size_t)bbat * DD + col] = f2b(r);
        }
    }
}

// ---------------------------------------------------------------------------
// o_gemm: Y (f32) = ctx @ Wo^T + bo.  Same BK=64 + XOR-swizzle structure.
// ---------------------------------------------------------------------------
__global__ __launch_bounds__(256) void o_gemm(
    const u16* __restrict__ A, const u16* __restrict__ W,
    const float* __restrict__ bia, float* __restrict__ Y)
{
    __shared__ __align__(16) u16 As[128 * 64];
    __shared__ __align__(16) u16 Bs[128 * 64];

    const int tid = threadIdx.x;
    const int m0 = blockIdx.x * 128;
    const int n0 = blockIdx.y * 128;

    const int wave = tid >> 6;
    const int lane = tid & 63;

    const int srow = wave * 8 + (lane >> 3);
    const int scol = ((lane & 7) ^ (lane >> 3)) * 8;
    const u16* srcA = A + (size_t)(m0 + srow) * DD + scol;
    const u16* srcB = W + (size_t)(n0 + srow) * DD + scol;

    char* ldsA = (char*)As + wave * 1024;
    char* ldsB = (char*)Bs + wave * 1024;

    const int wm = (wave >> 1) * 64;
    const int wn = (wave & 1) * 64;
    const int lrow = lane & 15;
    const int q4 = lane >> 4;
    const int soff0 = (q4 ^ (lrow & 7)) * 16;

    f32x4 acc[4][4] = {};

    for (int k0 = 0; k0 < DD; k0 += 64) {
        __syncthreads();
#pragma unroll
        for (int i = 0; i < 4; ++i) {
            const size_t go = (size_t)i * 32 * DD;
            load_lds16(srcA + go, ldsA + i * 4096);
            load_lds16(srcB + go, ldsB + i * 4096);
        }
        srcA += 64; srcB += 64;
        __syncthreads();

#pragma unroll
        for (int kk = 0; kk < 2; ++kk) {
            const int so = soff0 ^ (kk * 64);
            bf16x8 af[4], bfr[4];
#pragma unroll
            for (int i = 0; i < 4; ++i)
                af[i] = *(const bf16x8*)((const char*)As + (wm + i * 16 + lrow) * 128 + so);
#pragma unroll
            for (int i = 0; i < 4; ++i)
                bfr[i] = *(const bf16x8*)((const char*)Bs + (wn + i * 16 + lrow) * 128 + so);
#pragma unroll
            for (int mi = 0; mi < 4; ++mi)
#pragma unroll
                for (int ni = 0; ni < 4; ++ni)
                    acc[mi][ni] = __builtin_amdgcn_mfma_f32_16x16x32_bf16(af[mi], bfr[ni], acc[mi][ni], 0, 0, 0);
        }
    }

#pragma unroll
    for (int mi = 0; mi < 4; ++mi) {
#pragma unroll
        for (int r = 0; r < 4; ++r) {
            const int grow = m0 + wm + mi * 16 + (lane >> 4) * 4 + r;
#pragma unroll
            for (int ni = 0; ni < 4; ++ni) {
                const int gcol = n0 + wn + ni * 16 + (lane & 15);
                Y[(size_t)grow * DD + gcol] = acc[mi][ni][r] + bia[gcol];
            }
        }
    }
}

// ---------------------------------------------------------------------------
// ln_kernel: residual mean + LayerNorm.  One block per row; all f32 I/O.
// ---------------------------------------------------------------------------
__global__ __launch_bounds__(256) void ln_kernel(
    const float* __restrict__ Y,
    const float* __restrict__ e0, const float* __restrict__ e1,
    const float* __restrict__ e2, const float* __restrict__ e3,
    const float* __restrict__ gamma, const float* __restrict__ beta,
    float* __restrict__ out)
{
    const int r = blockIdx.x;
    const int tid = threadIdx.x;
    const int c = tid * 8;
    const size_t base = (size_t)r * DD + c;

    float v[8];
    {
        float4 y0 = *(const float4*)(Y + base);
        float4 y1 = *(const float4*)(Y + base + 4);
        float a[8] = {0, 0, 0, 0, 0, 0, 0, 0};
        const float* eps[4] = {e0, e1, e2, e3};
#pragma unroll
        for (int qq = 0; qq < 4; ++qq) {
            float4 p0 = *(const float4*)(eps[qq] + base);
            float4 p1 = *(const float4*)(eps[qq] + base + 4);
            a[0] += p0.x; a[1] += p0.y; a[2] += p0.z; a[3] += p0.w;
            a[4] += p1.x; a[5] += p1.y; a[6] += p1.z; a[7] += p1.w;
        }
        float yv[8] = {y0.x, y0.y, y0.z, y0.w, y1.x, y1.y, y1.z, y1.w};
#pragma unroll
        for (int i = 0; i < 8; ++i) v[i] = yv[i] + 0.25f * a[i];
    }

    float s = 0.f, sq = 0.f;
#pragma unroll
    for (int i = 0; i < 8; ++i) { s += v[i]; sq += v[i] * v[i]; }
#pragma unroll
    for (int off = 32; off >= 1; off >>= 1) {
        s += __shfl_xor(s, off);
        sq += __shfl_xor(sq, off);
    }
    __shared__ float sh[8];
    const int lane = tid & 63, wv = tid >> 6;
    if (lane == 0) { sh[wv] = s; sh[4 + wv] = sq; }
    __syncthreads();
    s = sh[0] + sh[1] + sh[2] + sh[3];
    sq = sh[4] + sh[5] + sh[6] + sh[7];

    const float invD = 1.0f / 2048.0f;
    const float mu = s * invD;
    const float rs = rsqrtf(sq * invD - mu * mu + 1e-5f);

    float4 g0 = *(const float4*)(gamma + c);
    float4 g1 = *(const float4*)(gamma + c + 4);
    float4 b0 = *(const float4*)(beta + c);
    float4 b1 = *(const float4*)(beta + c + 4);
    float gg[8] = {g0.x, g0.y, g0.z, g0.w, g1.x, g1.y, g1.z, g1.w};
    float bb[8] = {b0.x, b0.y, b0.z, b0.w, b1.x, b1.y, b1.z, b1.w};

    float o[8];
#pragma unroll
    for (int i = 0; i < 8; ++i) o[i] = (v[i] - mu) * rs * gg[i] + bb[i];
    *(float4*)(out + base)     = make_float4(o[0], o[1], o[2], o[3]);
    *(float4*)(out + base + 4) = make_float4(o[4], o[5], o[6], o[7]);
}

// ---------------------------------------------------------------------------
extern "C" void kernel_launch(void* const* d_in, const int* in_sizes, int n_in,
                              void* d_out, int out_size, void* d_ws, size_t ws_size,
                              hipStream_t stream)
{
    const float* e0   = (const float*)d_in[0];
    const float* e1   = (const float*)d_in[1];
    const float* e2   = (const float*)d_in[2];
    const float* e3   = (const float*)d_in[3];
    const float* qual = (const float*)d_in[4];
    const float* Wq   = (const float*)d_in[5];
    const float* bq   = (const float*)d_in[6];
    const float* Wk   = (const float*)d_in[7];
    const float* bk   = (const float*)d_in[8];
    const float* Wv   = (const float*)d_in[9];
    const float* bv   = (const float*)d_in[10];
    const float* Wo   = (const float*)d_in[11];
    const float* bo   = (const float*)d_in[12];
    const float* gm   = (const float*)d_in[13];
    const float* bt   = (const float*)d_in[14];

    const size_t WD = (size_t)DD * DD;            // 4,194,304
    const size_t MQ = (size_t)BB * NTT * DD;      // 33,554,432
    const size_t ED = (size_t)BB * DD;            // 8,388,608

    // workspace (u16 units): Ebf 67.1MB + W4 33.6MB + ctx 16.8MB + Y 33.6MB
    u16* Ebf = (u16*)d_ws;                        // MQ
    u16* W4  = Ebf + MQ;                          // 4*WD  (q,k,v,o)
    u16* ctx = W4 + 4 * WD;                       // ED
    float* Y = (float*)(ctx + ED);                // ED floats

    // stage 0: all conversions in one dispatch
    cvt_all<<<dim3(24576), 256, 0, stream>>>(e0, e1, e2, e3, Wq, Wk, Wv, Wo,
                                             Ebf, W4);

    // stage 1: fused QKV projection + attention -> ctx (B x D)
    qkv_attn<<<dim3(16, 128), 256, 0, stream>>>(Ebf, W4, W4 + WD, W4 + 2 * WD,
                                                bq, bk, bv, qual, ctx);

    // stage 2: O projection -> Y f32
    o_gemm<<<dim3(32, 16), 256, 0, stream>>>(ctx, W4 + 3 * WD, bo, Y);

    // stage 3: residual mean + LayerNorm
    ln_kernel<<<dim3(4096), 256, 0, stream>>>(Y, e0, e1, e2, e3, gm, bt,
                                              (float*)d_out);
}

// Round 3
// 621.597 us; speedup vs baseline: 1.1646x; 1.1646x over previous
//
#include <hip/hip_runtime.h>
#include <cstdint>
#include <cstddef>

// Problem constants
#define BB 4096
#define DD 2048
#define NHH 16
#define NTT 4
#define DKK 128

using u16 = unsigned short;
using u32 = unsigned int;

typedef __bf16 bf16x8 __attribute__((ext_vector_type(8)));
typedef float f32x4 __attribute__((ext_vector_type(4)));

__device__ __forceinline__ float b2f(u16 u) {
    union { float f; u32 i; } c; c.i = ((u32)u) << 16; return c.f;
}
__device__ __forceinline__ u16 f2b(float f) {
    union { float f; u32 i; } c; c.f = f;
    u32 x = c.i;
    u32 r = (x + 0x7fffu + ((x >> 16) & 1u)) >> 16;  // RNE
    return (u16)r;
}
// pack two f32 -> two bf16 (round-half-up via +0x8000, v_perm byte select)
__device__ __forceinline__ u32 pk(float lo, float hi) {
    u32 a = __builtin_bit_cast(u32, lo) + 0x8000u;
    u32 b = __builtin_bit_cast(u32, hi) + 0x8000u;
    return __builtin_amdgcn_perm(b, a, 0x07060302u);  // {b[31:16], a[31:16]}
}

__device__ __forceinline__ void load_lds16(const void* g, void* l) {
    __builtin_amdgcn_global_load_lds((const __attribute__((address_space(1))) void*)g,
                                     (__attribute__((address_space(3))) void*)l,
                                     16, 0, 0);
}

// ---------------------------------------------------------------------------
// cvt_all: blocks 0..4095: one block per BATCH -> converts 4 evidence rows to
// Ebf (M-interleaved rows 4b+t) AND writes resid = 0.25*sum_t H (f32), so
// ln_kernel does not re-read 134 MB of f32 evidence.
// blocks 4096..12287: weights Wq/Wk/Wv/Wo -> W4 (2048 rows each).
// ---------------------------------------------------------------------------
__global__ __launch_bounds__(256) void cvt_all(
    const float* __restrict__ e0, const float* __restrict__ e1,
    const float* __restrict__ e2, const float* __restrict__ e3,
    const float* __restrict__ Wq, const float* __restrict__ Wk,
    const float* __restrict__ Wv, const float* __restrict__ Wo,
    u16* __restrict__ Ebf, u16* __restrict__ W4, float* __restrict__ resid)
{
    const int blk = blockIdx.x;
    const int tid = threadIdx.x;
    if (blk < 4096) {
        const int b = blk;
        const int c = tid * 8;
        const size_t rb = (size_t)b * DD + c;
        const float* eps[4] = {e0, e1, e2, e3};
        float a8[8] = {0, 0, 0, 0, 0, 0, 0, 0};
#pragma unroll
        for (int t = 0; t < 4; ++t) {
            float4 p0 = *(const float4*)(eps[t] + rb);
            float4 p1 = *(const float4*)(eps[t] + rb + 4);
            u16* dst = Ebf + ((size_t)(b * 4 + t)) * DD + c;
            *(uint4*)dst = make_uint4(pk(p0.x, p0.y), pk(p0.z, p0.w),
                                      pk(p1.x, p1.y), pk(p1.z, p1.w));
            a8[0] += p0.x; a8[1] += p0.y; a8[2] += p0.z; a8[3] += p0.w;
            a8[4] += p1.x; a8[5] += p1.y; a8[6] += p1.z; a8[7] += p1.w;
        }
        *(float4*)(resid + rb)     = make_float4(a8[0] * 0.25f, a8[1] * 0.25f,
                                                 a8[2] * 0.25f, a8[3] * 0.25f);
        *(float4*)(resid + rb + 4) = make_float4(a8[4] * 0.25f, a8[5] * 0.25f,
                                                 a8[6] * 0.25f, a8[7] * 0.25f);
    } else {
        const int wb = blk - 4096;           // 0..8191
        const int w = wb >> 11;              // 0..3
        const float* src = (w == 0) ? Wq : (w == 1) ? Wk : (w == 2) ? Wv : Wo;
        u16* dst = W4 + (size_t)w * DD * DD;
        const size_t i = (size_t)(wb & 2047) * 2048 + tid * 8;
        float4 a = *(const float4*)(src + i);
        float4 c2 = *(const float4*)(src + i + 4);
        *(uint4*)(dst + i) = make_uint4(pk(a.x, a.y), pk(a.z, a.w),
                                        pk(c2.x, c2.y), pk(c2.z, c2.w));
    }
}

// ---------------------------------------------------------------------------
// qkv_attn: fused Q/K/V projection + quality-gated softmax + V-combine.
// grid (16, 128): x = head h (n-tile = 128 cols = one head), y = m-tile.
// BK=64 (128B LDS rows) with XOR swizzle (slot ^= row&7), staged linearly by
// global_load_lds with a pre-swizzled per-lane source column (rule #21).
//
// Wave tiling: 2x2 waves of 64M x 64N.  B-frag reuse = 4 (LDS-read pipe was
// co-critical with MFMA at the 32x128 tiling).  To avoid R2's scratch spill
// (192 acc + 48 live B-frags > 256 VGPR budget), the inner step is SEQUENCED
// per matrix: {load bQ[4]; 16 Q-MFMAs} |sched_barrier| {load bK[4]; ...}
// |sched_barrier| {load bV[4]; ...}.  Peak liveness ~235 regs.  Cross-group
// lgkm latency is hidden by the co-resident wave (2 waves/SIMD).
// Score dot completes via an LDS exchange between N-partner waves (w^1).
// ---------------------------------------------------------------------------
__global__ __launch_bounds__(256, 2) void qkv_attn(
    const u16* __restrict__ Ebf,
    const u16* __restrict__ Wqb, const u16* __restrict__ Wkb,
    const u16* __restrict__ Wvb,
    const float* __restrict__ bq, const float* __restrict__ bk,
    const float* __restrict__ bv, const float* __restrict__ qual,
    u16* __restrict__ ctx)
{
    __shared__ __align__(16) u16 As [128 * 64];
    __shared__ __align__(16) u16 BQs[128 * 64];
    __shared__ __align__(16) u16 BKs[128 * 64];
    __shared__ __align__(16) u16 BVs[128 * 64];
    __shared__ float exch[4][4][4][16];   // [wave][mi][quad][t*4+j]

    const int tid = threadIdx.x;
    const int h = blockIdx.x;            // head = n-tile
    const int m0 = blockIdx.y * 128;
    const int n0 = h * 128;

    const int wave = tid >> 6;
    const int lane = tid & 63;

    // staging: call i covers rows i*32..i*32+31; lane l of wave w owns
    // row i*32 + w*8 + (l>>3), LDS slot l&7.  Source chunk = (l&7)^(l>>3).
    const int srow = wave * 8 + (lane >> 3);
    const int scol = ((lane & 7) ^ (lane >> 3)) * 8;     // u16 units
    const u16* srcA = Ebf + (size_t)(m0 + srow) * DD + scol;
    const u16* srcQ = Wqb + (size_t)(n0 + srow) * DD + scol;
    const u16* srcK = Wkb + (size_t)(n0 + srow) * DD + scol;
    const u16* srcV = Wvb + (size_t)(n0 + srow) * DD + scol;

    char* ldsA = (char*)As  + wave * 1024;
    char* ldsQ = (char*)BQs + wave * 1024;
    char* ldsK = (char*)BKs + wave * 1024;
    char* ldsV = (char*)BVs + wave * 1024;

    const int lrow = lane & 15;
    const int q4 = lane >> 4;
    const int wm = (wave >> 1) * 64;     // wave's 64 M-rows
    const int wn = (wave & 1) * 64;      // wave's 64 N-cols (half head)
    // byte offset of this lane's 16B slot within a 128B row (kk=0); kk=1 is ^64
    const int soff0 = (q4 ^ (lrow & 7)) * 16;

    f32x4 aQ[4][4] = {};
    f32x4 aK[4][4] = {};
    f32x4 aV[4][4] = {};

    for (int k0 = 0; k0 < DD; k0 += 64) {
        __syncthreads();
#pragma unroll
        for (int i = 0; i < 4; ++i) {
            const size_t go = (size_t)i * 32 * DD;
            load_lds16(srcA + go, ldsA + i * 4096);
            load_lds16(srcQ + go, ldsQ + i * 4096);
            load_lds16(srcK + go, ldsK + i * 4096);
            load_lds16(srcV + go, ldsV + i * 4096);
        }
        srcA += 64; srcQ += 64; srcK += 64; srcV += 64;
        __syncthreads();

#pragma unroll
        for (int kk = 0; kk < 2; ++kk) {
            const int so = soff0 ^ (kk * 64);
            bf16x8 af[4];
#pragma unroll
            for (int mi = 0; mi < 4; ++mi)
                af[mi] = *(const bf16x8*)((const char*)As + (wm + mi * 16 + lrow) * 128 + so);
            {
                bf16x8 b4[4];
#pragma unroll
                for (int ni = 0; ni < 4; ++ni)
                    b4[ni] = *(const bf16x8*)((const char*)BQs + (wn + ni * 16 + lrow) * 128 + so);
#pragma unroll
                for (int mi = 0; mi < 4; ++mi)
#pragma unroll
                    for (int ni = 0; ni < 4; ++ni)
                        aQ[mi][ni] = __builtin_amdgcn_mfma_f32_16x16x32_bf16(af[mi], b4[ni], aQ[mi][ni], 0, 0, 0);
            }
            __builtin_amdgcn_sched_barrier(0);
            {
                bf16x8 b4[4];
#pragma unroll
                for (int ni = 0; ni < 4; ++ni)
                    b4[ni] = *(const bf16x8*)((const char*)BKs + (wn + ni * 16 + lrow) * 128 + so);
#pragma unroll
                for (int mi = 0; mi < 4; ++mi)
#pragma unroll
                    for (int ni = 0; ni < 4; ++ni)
                        aK[mi][ni] = __builtin_amdgcn_mfma_f32_16x16x32_bf16(af[mi], b4[ni], aK[mi][ni], 0, 0, 0);
            }
            __builtin_amdgcn_sched_barrier(0);
            {
                bf16x8 b4[4];
#pragma unroll
                for (int ni = 0; ni < 4; ++ni)
                    b4[ni] = *(const bf16x8*)((const char*)BVs + (wn + ni * 16 + lrow) * 128 + so);
#pragma unroll
                for (int mi = 0; mi < 4; ++mi)
#pragma unroll
                    for (int ni = 0; ni < 4; ++ni)
                        aV[mi][ni] = __builtin_amdgcn_mfma_f32_16x16x32_bf16(af[mi], b4[ni], aV[mi][ni], 0, 0, 0);
            }
            __builtin_amdgcn_sched_barrier(0);
        }
    }

    // ---- epilogue: scores -> cross-wave sum -> softmax -> V combine ----
    const int quad = lane >> 4;
    const int lcol = lane & 15;

    float qb[4], kb[4], vb[4];
#pragma unroll
    for (int ni = 0; ni < 4; ++ni) {
        const int col = n0 + wn + ni * 16 + lcol;
        qb[ni] = bq[col]; kb[ni] = bk[col]; vb[ni] = bv[col];
    }

    // Phase A: per mi, partial scores over this wave's 64 cols -> exch
#pragma unroll
    for (int mi = 0; mi < 4; ++mi) {
        float ps[4][4];
#pragma unroll
        for (int t = 0; t < 4; ++t)
#pragma unroll
            for (int j = 0; j < 4; ++j) ps[t][j] = 0.f;

#pragma unroll
        for (int ni = 0; ni < 4; ++ni) {
            float qv[4], kv[4];
#pragma unroll
            for (int t = 0; t < 4; ++t) {
                qv[t] = aQ[mi][ni][t] + qb[ni];
                kv[t] = aK[mi][ni][t] + kb[ni];
            }
#pragma unroll
            for (int t = 0; t < 4; ++t)
#pragma unroll
                for (int j = 0; j < 4; ++j) ps[t][j] += qv[t] * kv[j];
        }
        // butterfly over the 16 col-lanes (bits 0..3 of lane)
#pragma unroll
        for (int t = 0; t < 4; ++t)
#pragma unroll
            for (int j = 0; j < 4; ++j) {
                ps[t][j] += __shfl_xor(ps[t][j], 1);
                ps[t][j] += __shfl_xor(ps[t][j], 2);
                ps[t][j] += __shfl_xor(ps[t][j], 4);
                ps[t][j] += __shfl_xor(ps[t][j], 8);
            }
        // one lane per quad writes the 16 values with STATIC indices
        if (lcol == 0) {
#pragma unroll
            for (int t = 0; t < 4; ++t)
#pragma unroll
                for (int j = 0; j < 4; ++j)
                    exch[wave][mi][quad][t * 4 + j] = ps[t][j];
        }
    }
    __syncthreads();

    // Phase B: full scores (own + N-partner) -> softmax -> V combine
    const float scale = 0.08838834764831845f;   // 1/sqrt(128)
#pragma unroll
    for (int mi = 0; mi < 4; ++mi) {
        const int bbat = (m0 >> 2) + (wave >> 1) * 16 + mi * 4 + quad;

        float s16[16];
#pragma unroll
        for (int v = 0; v < 16; ++v)
            s16[v] = exch[wave][mi][quad][v] + exch[wave ^ 1][mi][quad][v];

        float qj[4];
#pragma unroll
        for (int j = 0; j < 4; ++j) qj[j] = qual[bbat * 4 + j] * scale;

        float wsum[4] = {0.f, 0.f, 0.f, 0.f};
#pragma unroll
        for (int t = 0; t < 4; ++t) {
            float sm[4]; float mx = -1e30f;
#pragma unroll
            for (int j = 0; j < 4; ++j) { sm[j] = s16[t * 4 + j] * qj[j]; mx = fmaxf(mx, sm[j]); }
            float ex[4]; float se = 0.f;
#pragma unroll
            for (int j = 0; j < 4; ++j) { ex[j] = __expf(sm[j] - mx); se += ex[j]; }
            const float inv = 0.25f / se;
#pragma unroll
            for (int j = 0; j < 4; ++j) wsum[j] += ex[j] * inv;
        }

        // ctx[bbat][col] = sum_j wsum[j] * Vproj[4b+j][col] + bv[col]
        // (sum_j wsum[j] == 1, so bias coefficient is exactly 1)
#pragma unroll
        for (int ni = 0; ni < 4; ++ni) {
            const int col = n0 + wn + ni * 16 + lcol;
            float r = wsum[0] * aV[mi][ni][0] + wsum[1] * aV[mi][ni][1]
                    + wsum[2] * aV[mi][ni][2] + wsum[3] * aV[mi][ni][3] + vb[ni];
            ctx[(size_t)bbat * DD + col] = f2b(r);
        }
    }
}

// ---------------------------------------------------------------------------
// o_gemm: Y (f32) = ctx @ Wo^T + bo.  Same BK=64 + XOR-swizzle structure.
// ---------------------------------------------------------------------------
__global__ __launch_bounds__(256) void o_gemm(
    const u16* __restrict__ A, const u16* __restrict__ W,
    const float* __restrict__ bia, float* __restrict__ Y)
{
    __shared__ __align__(16) u16 As[128 * 64];
    __shared__ __align__(16) u16 Bs[128 * 64];

    const int tid = threadIdx.x;
    const int m0 = blockIdx.x * 128;
    const int n0 = blockIdx.y * 128;

    const int wave = tid >> 6;
    const int lane = tid & 63;

    const int srow = wave * 8 + (lane >> 3);
    const int scol = ((lane & 7) ^ (lane >> 3)) * 8;
    const u16* srcA = A + (size_t)(m0 + srow) * DD + scol;
    const u16* srcB = W + (size_t)(n0 + srow) * DD + scol;

    char* ldsA = (char*)As + wave * 1024;
    char* ldsB = (char*)Bs + wave * 1024;

    const int wm = (wave >> 1) * 64;
    const int wn = (wave & 1) * 64;
    const int lrow = lane & 15;
    const int q4 = lane >> 4;
    const int soff0 = (q4 ^ (lrow & 7)) * 16;

    f32x4 acc[4][4] = {};

    for (int k0 = 0; k0 < DD; k0 += 64) {
        __syncthreads();
#pragma unroll
        for (int i = 0; i < 4; ++i) {
            const size_t go = (size_t)i * 32 * DD;
            load_lds16(srcA + go, ldsA + i * 4096);
            load_lds16(srcB + go, ldsB + i * 4096);
        }
        srcA += 64; srcB += 64;
        __syncthreads();

#pragma unroll
        for (int kk = 0; kk < 2; ++kk) {
            const int so = soff0 ^ (kk * 64);
            bf16x8 af[4], bfr[4];
#pragma unroll
            for (int i = 0; i < 4; ++i)
                af[i] = *(const bf16x8*)((const char*)As + (wm + i * 16 + lrow) * 128 + so);
#pragma unroll
            for (int i = 0; i < 4; ++i)
                bfr[i] = *(const bf16x8*)((const char*)Bs + (wn + i * 16 + lrow) * 128 + so);
#pragma unroll
            for (int mi = 0; mi < 4; ++mi)
#pragma unroll
                for (int ni = 0; ni < 4; ++ni)
                    acc[mi][ni] = __builtin_amdgcn_mfma_f32_16x16x32_bf16(af[mi], bfr[ni], acc[mi][ni], 0, 0, 0);
        }
    }

#pragma unroll
    for (int mi = 0; mi < 4; ++mi) {
#pragma unroll
        for (int r = 0; r < 4; ++r) {
            const int grow = m0 + wm + mi * 16 + (lane >> 4) * 4 + r;
#pragma unroll
            for (int ni = 0; ni < 4; ++ni) {
                const int gcol = n0 + wn + ni * 16 + (lane & 15);
                Y[(size_t)grow * DD + gcol] = acc[mi][ni][r] + bia[gcol];
            }
        }
    }
}

// ---------------------------------------------------------------------------
// ln_kernel: residual add (precomputed resid) + LayerNorm.  One block per row.
// ---------------------------------------------------------------------------
__global__ __launch_bounds__(256) void ln_kernel(
    const float* __restrict__ Y,
    const float* __restrict__ resid,
    const float* __restrict__ gamma, const float* __restrict__ beta,
    float* __restrict__ out)
{
    const int r = blockIdx.x;
    const int tid = threadIdx.x;
    const int c = tid * 8;
    const size_t base = (size_t)r * DD + c;

    float v[8];
    {
        float4 y0 = *(const float4*)(Y + base);
        float4 y1 = *(const float4*)(Y + base + 4);
        float4 r0 = *(const float4*)(resid + base);
        float4 r1 = *(const float4*)(resid + base + 4);
        v[0] = y0.x + r0.x; v[1] = y0.y + r0.y; v[2] = y0.z + r0.z; v[3] = y0.w + r0.w;
        v[4] = y1.x + r1.x; v[5] = y1.y + r1.y; v[6] = y1.z + r1.z; v[7] = y1.w + r1.w;
    }

    float s = 0.f, sq = 0.f;
#pragma unroll
    for (int i = 0; i < 8; ++i) { s += v[i]; sq += v[i] * v[i]; }
#pragma unroll
    for (int off = 32; off >= 1; off >>= 1) {
        s += __shfl_xor(s, off);
        sq += __shfl_xor(sq, off);
    }
    __shared__ float sh[8];
    const int lane = tid & 63, wv = tid >> 6;
    if (lane == 0) { sh[wv] = s; sh[4 + wv] = sq; }
    __syncthreads();
    s = sh[0] + sh[1] + sh[2] + sh[3];
    sq = sh[4] + sh[5] + sh[6] + sh[7];

    const float invD = 1.0f / 2048.0f;
    const float mu = s * invD;
    const float rs = rsqrtf(sq * invD - mu * mu + 1e-5f);

    float4 g0 = *(const float4*)(gamma + c);
    float4 g1 = *(const float4*)(gamma + c + 4);
    float4 b0 = *(const float4*)(beta + c);
    float4 b1 = *(const float4*)(beta + c + 4);
    float gg[8] = {g0.x, g0.y, g0.z, g0.w, g1.x, g1.y, g1.z, g1.w};
    float bb[8] = {b0.x, b0.y, b0.z, b0.w, b1.x, b1.y, b1.z, b1.w};

    float o[8];
#pragma unroll
    for (int i = 0; i < 8; ++i) o[i] = (v[i] - mu) * rs * gg[i] + bb[i];
    *(float4*)(out + base)     = make_float4(o[0], o[1], o[2], o[3]);
    *(float4*)(out + base + 4) = make_float4(o[4], o[5], o[6], o[7]);
}

// ---------------------------------------------------------------------------
extern "C" void kernel_launch(void* const* d_in, const int* in_sizes, int n_in,
                              void* d_out, int out_size, void* d_ws, size_t ws_size,
                              hipStream_t stream)
{
    const float* e0   = (const float*)d_in[0];
    const float* e1   = (const float*)d_in[1];
    const float* e2   = (const float*)d_in[2];
    const float* e3   = (const float*)d_in[3];
    const float* qual = (const float*)d_in[4];
    const float* Wq   = (const float*)d_in[5];
    const float* bq   = (const float*)d_in[6];
    const float* Wk   = (const float*)d_in[7];
    const float* bk   = (const float*)d_in[8];
    const float* Wv   = (const float*)d_in[9];
    const float* bv   = (const float*)d_in[10];
    const float* Wo   = (const float*)d_in[11];
    const float* bo   = (const float*)d_in[12];
    const float* gm   = (const float*)d_in[13];
    const float* bt   = (const float*)d_in[14];

    const size_t WD = (size_t)DD * DD;            // 4,194,304
    const size_t MQ = (size_t)BB * NTT * DD;      // 33,554,432
    const size_t ED = (size_t)BB * DD;            // 8,388,608

    // workspace (u16 units): Ebf 67.1MB + W4 33.6MB + ctx 16.8MB
    // + Y 33.6MB f32 + resid 33.6MB f32 = 184.6 MB total.
    u16* Ebf = (u16*)d_ws;                        // MQ
    u16* W4  = Ebf + MQ;                          // 4*WD  (q,k,v,o)
    u16* ctx = W4 + 4 * WD;                       // ED
    float* Y = (float*)(ctx + ED);                // ED floats
    float* resid = Y + ED;                        // ED floats

    // stage 0: all conversions + residual mean in one dispatch
    cvt_all<<<dim3(12288), 256, 0, stream>>>(e0, e1, e2, e3, Wq, Wk, Wv, Wo,
                                             Ebf, W4, resid);

    // stage 1: fused QKV projection + attention -> ctx (B x D)
    qkv_attn<<<dim3(16, 128), 256, 0, stream>>>(Ebf, W4, W4 + WD, W4 + 2 * WD,
                                                bq, bk, bv, qual, ctx);

    // stage 2: O projection -> Y f32
    o_gemm<<<dim3(32, 16), 256, 0, stream>>>(ctx, W4 + 3 * WD, bo, Y);

    // stage 3: residual add + LayerNorm
    ln_kernel<<<dim3(4096), 256, 0, stream>>>(Y, resid, gm, bt,
                                              (float*)d_out);
}